// Round 7
// baseline (102.219 us; speedup 1.0000x reference)
//
#include <hip/hip_runtime.h>
#include <math.h>

#define C_IN  128
#define H_IN  56
#define W_IN  56
#define HW_IN (H_IN * W_IN)          // 3136
#define N_IN  8
#define O_MID 64
#define KK    5
#define NCLS  2

// ws layout (floats):
//   [0, 7680)    Weff[5][128][12]  (slot = dj*2+k; 10,11 pad)
//   [7680,7682)  beff[2]
//   [8192, ...)  G[p][n][hw][k]  p=di*5+dj: 25*8*3136*2 = 1,254,400 fl (~5 MB)
#define WEFF_STRIDE 12
#define WEFF_SIZE   (5 * C_IN * WEFF_STRIDE)
#define G_BASE      8192

// ---------------- k_weff: fold O=64 away ----------------
__global__ __launch_bounds__(256) void k_weff(const float* __restrict__ Wt,
                                              const float* __restrict__ bias,
                                              const float* __restrict__ Wlin,
                                              const float* __restrict__ blin,
                                              float* __restrict__ ws) {
    const int b = blockIdx.x;       // 0..49
    const int p = b >> 1;
    const int k = b & 1;
    const int t = threadIdx.x;
    const int c = t & 127;
    const int oh = t >> 7;
    float s = 0.f;
#pragma unroll
    for (int oo = 0; oo < 32; ++oo) {
        const int o = oh * 32 + oo;
        s += Wlin[k * O_MID + o] * Wt[(o * C_IN + c) * (KK * KK) + p];
    }
    __shared__ float part[256];
    part[t] = s;
    __syncthreads();
    if (t < 128) {
        const int di = p / KK;
        const int dj = p - di * KK;
        ws[(di * C_IN + c) * WEFF_STRIDE + dj * 2 + k] = part[c] + part[c + 128];
    }
    if (p == 0 && t < 64) {
        float v = Wlin[k * O_MID + t] * bias[t];
#pragma unroll
        for (int off = 32; off; off >>= 1) v += __shfl_down(v, off, 64);
        if (t == 0) ws[WEFF_SIZE + k] = v + blin[k];
    }
}

// ---------------- k_gemm: G[p][n][hw][k] = sum_c x[n][c][hw] * Weff[di][c][dj*2+k] ----------------
// grid (49, 5, 8), 256 thr = 4 waves. All 4 waves share the same 64-px chunk;
// wave w handles channels [w*32, w*32+32). LDS combine, wave 0 stores.
__global__ __launch_bounds__(256) void k_gemm(const float* __restrict__ x,
                                              const float* __restrict__ ws,
                                              float* __restrict__ g) {
    __shared__ float red[3][64][11];     // pad 11: stride coprime 32 banks

    const int tid  = threadIdx.x;
    const int px   = tid & 63;
    const int w    = tid >> 6;
    const int hw   = blockIdx.x * 64 + px;
    const int di   = blockIdx.y;
    const int n    = blockIdx.z;

    const float* xc = x + (size_t)n * (C_IN * HW_IN) + (size_t)(w * 32) * HW_IN + hw;
    const float* wd = ws + di * (C_IN * WEFF_STRIDE) + (w * 32) * WEFF_STRIDE;

    float acc[5][2];
#pragma unroll
    for (int dj = 0; dj < 5; ++dj) { acc[dj][0] = 0.f; acc[dj][1] = 0.f; }

#pragma unroll 8
    for (int c = 0; c < 32; ++c) {
        const float xv = xc[(size_t)c * HW_IN];
        const float* wr = wd + c * WEFF_STRIDE;
#pragma unroll
        for (int dj = 0; dj < 5; ++dj) {
            acc[dj][0] = fmaf(xv, wr[dj * 2 + 0], acc[dj][0]);
            acc[dj][1] = fmaf(xv, wr[dj * 2 + 1], acc[dj][1]);
        }
    }

    if (w > 0) {
#pragma unroll
        for (int dj = 0; dj < 5; ++dj) {
            red[w - 1][px][dj * 2 + 0] = acc[dj][0];
            red[w - 1][px][dj * 2 + 1] = acc[dj][1];
        }
    }
    __syncthreads();
    if (w == 0) {
#pragma unroll
        for (int dj = 0; dj < 5; ++dj) {
            float v0 = acc[dj][0], v1 = acc[dj][1];
#pragma unroll
            for (int q = 0; q < 3; ++q) {
                v0 += red[q][px][dj * 2 + 0];
                v1 += red[q][px][dj * 2 + 1];
            }
            const int p = di * 5 + dj;
            *(float2*)&g[(((size_t)p * N_IN + n) * HW_IN + hw) * 2] = make_float2(v0, v1);
        }
    }
}

// ---------------- k_final: gather shifted G, abs-stats, output ----------------
// grid (49, 8), 64 threads. lane = out pixel within chunk.
__global__ __launch_bounds__(64) void k_final(const float* __restrict__ ws,
                                              const float* __restrict__ g,
                                              float* __restrict__ out) {
    const int lane = threadIdx.x;
    const int hw   = blockIdx.x * 64 + lane;
    const int n    = blockIdx.y;
    const int y    = hw / W_IN;
    const int x    = hw - y * W_IN;

    const float be0 = ws[WEFF_SIZE + 0];
    const float be1 = ws[WEFF_SIZE + 1];

    float A0 = 0.f, X0 = 0.f, Y0 = 0.f, C0 = 0.f;
    float A1 = 0.f, X1 = 0.f, Y1 = 0.f, C1 = 0.f;

#pragma unroll
    for (int di = 0; di < 5; ++di) {
        const int yy = y + di - 2;
        const bool rowok = (unsigned)yy < H_IN;
#pragma unroll
        for (int dj = 0; dj < 5; ++dj) {
            const int xx = x + dj - 2;
            const bool ok = rowok && ((unsigned)xx < W_IN);
            float2 gv = make_float2(0.f, 0.f);
            if (ok) {
                const int p = di * 5 + dj;
                gv = *(const float2*)&g[(((size_t)p * N_IN + n) * HW_IN + yy * W_IN + xx) * 2];
            }
            const float v0 = gv.x + be0;
            const float v1 = gv.y + be1;
            const float a0 = fabsf(v0);
            const float a1 = fabsf(v1);
            const float fdj = (float)(dj - 2);
            const float fdi = (float)(di - 2);
            A0 += a0; X0 = fmaf(a0, fdj, X0); Y0 = fmaf(a0, fdi, Y0); C0 += v0;
            A1 += a1; X1 = fmaf(a1, fdj, X1); Y1 = fmaf(a1, fdi, Y1); C1 += v1;
        }
    }

    const float xd0 = X0 / A0, yd0 = Y0 / A0;
    const float xd1 = X1 / A1, yd1 = Y1 / A1;
    const float o0 = C0 * expf(-0.5f * sqrtf(xd0 * xd0 + yd0 * yd0));
    const float o1 = C1 * expf(-0.5f * sqrtf(xd1 * xd1 + yd1 * yd1));
    *(float2*)&out[((size_t)n * HW_IN + hw) * 2] = make_float2(o0, o1);
}

extern "C" void kernel_launch(void* const* d_in, const int* in_sizes, int n_in,
                              void* d_out, int out_size, void* d_ws, size_t ws_size,
                              hipStream_t stream) {
    const float* x    = (const float*)d_in[0];
    const float* Wt   = (const float*)d_in[1];
    const float* bias = (const float*)d_in[2];
    const float* Wlin = (const float*)d_in[3];
    const float* blin = (const float*)d_in[4];
    float* ws = (float*)d_ws;

    k_weff<<<dim3(KK * KK * NCLS), dim3(256), 0, stream>>>(Wt, bias, Wlin, blin, ws);
    k_gemm<<<dim3(49, KK, N_IN), dim3(256), 0, stream>>>(x, ws, ws + G_BASE);
    k_final<<<dim3(49, N_IN), dim3(64), 0, stream>>>(ws, ws + G_BASE, (float*)d_out);
}

// Round 8
// 91.932 us; speedup vs baseline: 1.1119x; 1.1119x over previous
//
#include <hip/hip_runtime.h>
#include <math.h>

#define C_IN  128
#define H_IN  56
#define W_IN  56
#define HW_IN (H_IN * W_IN)          // 3136
#define N_IN  8
#define O_MID 64
#define KK    5
#define NCLS  2

// ws layout (floats):
//   [0, 7680)    Weff[5][128][12]  (slot = dj*2+k; 10,11 pad)
//   [7680,7682)  beff[2]
//   [8192, ...)  G2[half][p][n][hw][k] : 2 * 25*8*3136*2 fl (~10 MB)
#define WEFF_STRIDE 12
#define WEFF_SIZE   (5 * C_IN * WEFF_STRIDE)
#define G_BASE      8192
#define G_HALF      (25 * N_IN * HW_IN * 2)   // 1,254,400 fl

// ---------------- k_weff: fold O=64 away ----------------
__global__ __launch_bounds__(256) void k_weff(const float* __restrict__ Wt,
                                              const float* __restrict__ bias,
                                              const float* __restrict__ Wlin,
                                              const float* __restrict__ blin,
                                              float* __restrict__ ws) {
    const int b = blockIdx.x;       // 0..49
    const int p = b >> 1;
    const int k = b & 1;
    const int t = threadIdx.x;
    const int c = t & 127;
    const int oh = t >> 7;
    float s = 0.f;
#pragma unroll
    for (int oo = 0; oo < 32; ++oo) {
        const int o = oh * 32 + oo;
        s += Wlin[k * O_MID + o] * Wt[(o * C_IN + c) * (KK * KK) + p];
    }
    __shared__ float part[256];
    part[t] = s;
    __syncthreads();
    if (t < 128) {
        const int di = p / KK;
        const int dj = p - di * KK;
        ws[(di * C_IN + c) * WEFF_STRIDE + dj * 2 + k] = part[c] + part[c + 128];
    }
    if (p == 0 && t < 64) {
        float v = Wlin[k * O_MID + t] * bias[t];
#pragma unroll
        for (int off = 32; off; off >>= 1) v += __shfl_down(v, off, 64);
        if (t == 0) ws[WEFF_SIZE + k] = v + blin[k];
    }
}

// ---------------- k_gemm: half-K partial GEMM, single-wave blocks ----------------
// grid (98, 5, 8): bx = hw-chunk*2 + c-half. 64 threads = 1 wave, no barrier deps.
// G2[half][di*5+dj][n][hw][k] += sum over 64 channels.
__global__ __launch_bounds__(64) void k_gemm(const float* __restrict__ x,
                                             const float* __restrict__ ws,
                                             float* __restrict__ g) {
    __shared__ float wls[64 * WEFF_STRIDE];   // 3 KB half-slice of Weff[di]

    const int lane = threadIdx.x;
    const int bx   = blockIdx.x;
    const int hwc  = bx >> 1;
    const int half = bx & 1;
    const int hw   = hwc * 64 + lane;
    const int di   = blockIdx.y;
    const int n    = blockIdx.z;

    const float* wd = ws + di * (C_IN * WEFF_STRIDE) + half * 64 * WEFF_STRIDE;
#pragma unroll
    for (int r = 0; r < 3; ++r) {
        const int i = lane * 4 + r * 256;
        *(float4*)&wls[i] = *(const float4*)&wd[i];
    }
    __syncthreads();

    const float* xc = x + (size_t)n * (C_IN * HW_IN) + (size_t)(half * 64) * HW_IN + hw;

    float acc[5][2];
#pragma unroll
    for (int dj = 0; dj < 5; ++dj) { acc[dj][0] = 0.f; acc[dj][1] = 0.f; }

#pragma unroll
    for (int c8 = 0; c8 < 8; ++c8) {
        float xv[8];
#pragma unroll
        for (int u = 0; u < 8; ++u)
            xv[u] = xc[(size_t)(c8 * 8 + u) * HW_IN];
#pragma unroll
        for (int u = 0; u < 8; ++u) {
            const float* wr = &wls[(c8 * 8 + u) * WEFF_STRIDE];
#pragma unroll
            for (int dj = 0; dj < 5; ++dj) {
                acc[dj][0] = fmaf(xv[u], wr[dj * 2 + 0], acc[dj][0]);
                acc[dj][1] = fmaf(xv[u], wr[dj * 2 + 1], acc[dj][1]);
            }
        }
    }

#pragma unroll
    for (int dj = 0; dj < 5; ++dj) {
        const int p = di * 5 + dj;
        const size_t idx = ((size_t)half * G_HALF)
                         + (((size_t)p * N_IN + n) * HW_IN + hw) * 2;
        *(float2*)&g[idx] = make_float2(acc[dj][0], acc[dj][1]);
    }
}

// ---------------- k_final: gather both halves, abs-stats, output ----------------
// grid (49, 8), 64 threads. lane = out pixel within chunk.
__global__ __launch_bounds__(64) void k_final(const float* __restrict__ ws,
                                              const float* __restrict__ g,
                                              float* __restrict__ out) {
    const int lane = threadIdx.x;
    const int hw   = blockIdx.x * 64 + lane;
    const int n    = blockIdx.y;
    const int y    = hw / W_IN;
    const int x    = hw - y * W_IN;

    const float be0 = ws[WEFF_SIZE + 0];
    const float be1 = ws[WEFF_SIZE + 1];

    float A0 = 0.f, X0 = 0.f, Y0 = 0.f, C0 = 0.f;
    float A1 = 0.f, X1 = 0.f, Y1 = 0.f, C1 = 0.f;

#pragma unroll
    for (int di = 0; di < 5; ++di) {
        const int yy = y + di - 2;
        const bool rowok = (unsigned)yy < H_IN;
#pragma unroll
        for (int dj = 0; dj < 5; ++dj) {
            const int xx = x + dj - 2;
            const bool ok = rowok && ((unsigned)xx < W_IN);
            float2 ga = make_float2(0.f, 0.f);
            float2 gb = make_float2(0.f, 0.f);
            if (ok) {
                const int p = di * 5 + dj;
                const size_t base = (((size_t)p * N_IN + n) * HW_IN + yy * W_IN + xx) * 2;
                ga = *(const float2*)&g[base];
                gb = *(const float2*)&g[(size_t)G_HALF + base];
            }
            const float v0 = ga.x + gb.x + be0;
            const float v1 = ga.y + gb.y + be1;
            const float a0 = fabsf(v0);
            const float a1 = fabsf(v1);
            const float fdj = (float)(dj - 2);
            const float fdi = (float)(di - 2);
            A0 += a0; X0 = fmaf(a0, fdj, X0); Y0 = fmaf(a0, fdi, Y0); C0 += v0;
            A1 += a1; X1 = fmaf(a1, fdj, X1); Y1 = fmaf(a1, fdi, Y1); C1 += v1;
        }
    }

    const float xd0 = X0 / A0, yd0 = Y0 / A0;
    const float xd1 = X1 / A1, yd1 = Y1 / A1;
    const float o0 = C0 * expf(-0.5f * sqrtf(xd0 * xd0 + yd0 * yd0));
    const float o1 = C1 * expf(-0.5f * sqrtf(xd1 * xd1 + yd1 * yd1));
    *(float2*)&out[((size_t)n * HW_IN + hw) * 2] = make_float2(o0, o1);
}

extern "C" void kernel_launch(void* const* d_in, const int* in_sizes, int n_in,
                              void* d_out, int out_size, void* d_ws, size_t ws_size,
                              hipStream_t stream) {
    const float* x    = (const float*)d_in[0];
    const float* Wt   = (const float*)d_in[1];
    const float* bias = (const float*)d_in[2];
    const float* Wlin = (const float*)d_in[3];
    const float* blin = (const float*)d_in[4];
    float* ws = (float*)d_ws;

    k_weff<<<dim3(KK * KK * NCLS), dim3(256), 0, stream>>>(Wt, bias, Wlin, blin, ws);
    k_gemm<<<dim3(98, KK, N_IN), dim3(64), 0, stream>>>(x, ws, ws + G_BASE);
    k_final<<<dim3(49, N_IN), dim3(64), 0, stream>>>(ws, ws + G_BASE, (float*)d_out);
}